// Round 1
// 338.255 us; speedup vs baseline: 1.0032x; 1.0032x over previous
//
#include <hip/hip_runtime.h>

#define L  768
#define SD 384
#define PD 128
#define ROWS 4   // rows per phase1 block
#define TI 16    // i-rows per phase2 block
#define JPT 4    // j-rows per thread in phase2
#define TJ 32    // j-rows per phase2 block = 8 * JPT

typedef float vf4 __attribute__((ext_vector_type(4)));

// ws layout (floats): si[L*PD] | sj[L*PD] | u[L*PD] | v[L*PD]   (1.57 MB total)

__global__ __launch_bounds__(256) void phase1_kernel(
    const float* __restrict__ s,
    const float* __restrict__ wi, const float* __restrict__ bi,
    const float* __restrict__ wj, const float* __restrict__ bj,
    const float* __restrict__ wm, const float* __restrict__ bm,
    float* __restrict__ ws)
{
    __shared__ float s_t[ROWS][SD];          // 6 KB
    __shared__ float sij_t[2][ROWS][PD];     // 4 KB
    const int tid = threadIdx.x;
    const int r0  = blockIdx.x * ROWS;

    // stage 4 rows of s into LDS, coalesced
    for (int idx = tid; idx < ROWS * SD; idx += 256) {
        s_t[idx / SD][idx % SD] = s[(size_t)r0 * SD + idx];
    }
    __syncthreads();

    const int half = tid >> 7;        // wave-uniform: waves 0-1 -> si, waves 2-3 -> sj
    const int e    = tid & 127;       // output channel
    const float* wrow = (half ? wj : wi) + (size_t)e * SD;
    const float  bb   = (half ? bj : bi)[e];

    // si[r][e] / sj[r][e] = dot(s[r], w[e]) + b[e]
    float acc[ROWS] = {0.f, 0.f, 0.f, 0.f};
    const vf4* w4 = (const vf4*)wrow;
    for (int d4 = 0; d4 < SD / 4; ++d4) {
        const vf4 wv = w4[d4];
        #pragma unroll
        for (int r = 0; r < ROWS; ++r) {
            const vf4 sv = ((const vf4*)s_t[r])[d4];   // LDS broadcast, b128
            acc[r] += sv.x * wv.x + sv.y * wv.y + sv.z * wv.z + sv.w * wv.w;
        }
    }

    float* si_ws = ws;
    float* sj_ws = ws + (size_t)L * PD;
    float* u_ws  = ws + 2 * (size_t)L * PD;
    float* v_ws  = ws + 3 * (size_t)L * PD;

    float* sij_ws = half ? sj_ws : si_ws;
    #pragma unroll
    for (int r = 0; r < ROWS; ++r) {
        const float val = acc[r] + bb;
        sij_t[half][r][e] = val;
        sij_ws[(size_t)(r0 + r) * PD + e] = val;
    }
    __syncthreads();

    // u[r][e] = dot(si[r], wm[e, 0:128]) ; v[r][e] = dot(sj[r], wm[e, 128:256]) + bm[e]
    const vf4* wm4 = (const vf4*)(wm + (size_t)e * (2 * PD) + half * PD);
    float acc2[ROWS] = {0.f, 0.f, 0.f, 0.f};
    for (int d4 = 0; d4 < PD / 4; ++d4) {
        const vf4 wv = wm4[d4];
        #pragma unroll
        for (int r = 0; r < ROWS; ++r) {
            const vf4 sv = ((const vf4*)sij_t[half][r])[d4];
            acc2[r] += sv.x * wv.x + sv.y * wv.y + sv.z * wv.z + sv.w * wv.w;
        }
    }
    const float bm_e = bm[e];
    float* z_ws = half ? v_ws : u_ws;
    #pragma unroll
    for (int r = 0; r < ROWS; ++r) {
        z_ws[(size_t)(r0 + r) * PD + e] = acc2[r] + (half ? bm_e : 0.f);
    }
}

// out[i,j,e] = u[i,e] + v[j,e] + si[i,e]*sj[j,e]
//
// v2 changes vs the 339 µs version:
//  * JPT=4: each thread owns 4 j-rows (j0+jj+8k). One si/u load pair now feeds
//    4 stores (load:store bytes 1:2 instead of 2:1) -> fewer dependent stalls,
//    half the L2 read traffic.
//  * __builtin_nontemporal_store: the 302 MB output stream no longer
//    write-allocates in L2, so the 1.57 MB ws working set stays L2-resident
//    (theory: cached stores were sweeping the 4 MB/XCD L2 and evicting ws,
//    exposing HBM latency in front of every store).
//  * Wave store pattern unchanged: lanes (q=0..31, jj pair) cover a fully
//    contiguous 1 KB segment per store instruction (the 6.1 TB/s fill pattern).
__global__ __launch_bounds__(256) void phase2_kernel(
    const float* __restrict__ ws, float* __restrict__ out)
{
    const int i0 = blockIdx.y * TI;
    const int j0 = blockIdx.x * TJ;
    const int q  = threadIdx.x & 31;   // float4 index within 128 channels
    const int jj = threadIdx.x >> 5;   // 0..7

    const vf4* si = (const vf4*)(ws);
    const vf4* sj = (const vf4*)(ws + (size_t)L * PD);
    const vf4* u  = (const vf4*)(ws + 2 * (size_t)L * PD);
    const vf4* v  = (const vf4*)(ws + 3 * (size_t)L * PD);

    vf4 vj[JPT], sjj[JPT];
    #pragma unroll
    for (int k = 0; k < JPT; ++k) {
        const int j = j0 + jj + 8 * k;
        vj[k]  = v [(size_t)j * 32 + q];
        sjj[k] = sj[(size_t)j * 32 + q];
    }

    vf4* o = (vf4*)out;
    #pragma unroll 4
    for (int il = 0; il < TI; ++il) {
        const int i = i0 + il;
        const vf4 s4 = si[(size_t)i * 32 + q];
        const vf4 u4 = u [(size_t)i * 32 + q];
        #pragma unroll
        for (int k = 0; k < JPT; ++k) {
            const int j = j0 + jj + 8 * k;
            const vf4 z = u4 + vj[k] + s4 * sjj[k];
            __builtin_nontemporal_store(z, &o[((size_t)i * L + j) * 32 + q]);
        }
    }
}

extern "C" void kernel_launch(void* const* d_in, const int* in_sizes, int n_in,
                              void* d_out, int out_size, void* d_ws, size_t ws_size,
                              hipStream_t stream) {
    const float* s  = (const float*)d_in[0];
    const float* wi = (const float*)d_in[1];
    const float* bi = (const float*)d_in[2];
    const float* wj = (const float*)d_in[3];
    const float* bj = (const float*)d_in[4];
    const float* wm = (const float*)d_in[5];
    const float* bm = (const float*)d_in[6];
    float* out = (float*)d_out;
    float* ws  = (float*)d_ws;   // needs 4*L*PD*4 = 1.57 MB

    phase1_kernel<<<dim3(L / ROWS), 256, 0, stream>>>(s, wi, bi, wj, bj, wm, bm, ws);
    phase2_kernel<<<dim3(L / TJ, L / TI), 256, 0, stream>>>(ws, out);
}